// Round 3
// baseline (211.662 us; speedup 1.0000x reference)
//
#include <hip/hip_runtime.h>
#include <hip/hip_bf16.h>

// LDConv (deformable sampling + (N,1) conv + BN + SiLU) for MI355X.
//
// Round-16 = R15 (114.6 us) with phase 2 rebuilt BARRIER-FREE:
//  - R15 post-mortem: fusion helped only ~2us. Counters: MfmaUtil 16%,
//    VALU 26%, HBM 8%, occ 33% -> 8x above every roofline, all pipes idle.
//    Cause: 20+ __syncthreads per block lockstep 4 waves; every round waits
//    an L2 latency with only ~150cy of cover; stalls are correlated so
//    co-resident waves can't fill them. The LDS A-tile (and its barriers)
//    exists ONLY to transpose gathered rows into MFMA B-fragment layout.
//  - Fix: gather DIRECTLY in fragment layout. B-frag of 16x16x32: lane l
//    holds px (l&15), bytes kc*64+(l>>4)*16 of the combined row. Each lane
//    loads the 4 bilinear source rows' 16B slice at that offset, combines
//    in f32 (same ops as old COMB -> bit-identical), pk_bf16 -> B-frag in
//    registers. NO A_lds, NO transpose, ZERO barriers in the GEMM.
//  - New partition: each wave owns 16 px (pxh=wv&1) x 128 out-ch (oh=wv>>1):
//    acc 8xf32x4=32 regs. 36 kc-chunks, depth-1 Ga/Gb ping-pong (32 regs,
//    the proven GX/GY budget), sched_barrier(0) chunk fences pin liveness.
//    desc read per step from descL (LDS broadcast, loaded 2 chunks early).
//  - LDS 21.5KB (Btile 17KB + descL 4.5KB; off_lds overlays dead Btile)
//    -> 7 blocks/CU cap; VGPR ~100 (<=128 at (256,4)) -> waves drift free.
// Carried: phase-1 offset conv + descL (unchanged), XCD swizzle, BN folded
// into wf, fast SiLU, setprio around MFMA, launch_bounds(256,4).

typedef __attribute__((ext_vector_type(8))) short bf16x8;
typedef __attribute__((ext_vector_type(4))) float f32x4;
typedef __attribute__((ext_vector_type(2))) float f32x2;
typedef __attribute__((ext_vector_type(4))) unsigned int u32x4;

#define NHW 6400
#define NPIX 80

__device__ __forceinline__ unsigned short f2bf(float f){
  __hip_bfloat16 h = __float2bfloat16(f);
  unsigned short u; __builtin_memcpy(&u, &h, 2); return u;
}
__device__ __forceinline__ f32x2 bfp2f(unsigned int u){
  union { unsigned int i; float f; } a, b;
  a.i = u << 16; b.i = u & 0xffff0000u;
  f32x2 r; r.x = a.f; r.y = b.f; return r;
}
__device__ __forceinline__ unsigned pk_bf16(float a, float b){
  unsigned r;
  asm("v_cvt_pk_bf16_f32 %0, %1, %2" : "=v"(r) : "v"(a), "v"(b));
  return r;
}
__device__ __forceinline__ void splitbf(float v, unsigned short& hi, unsigned short& lo){
  hi = f2bf(v);
  union { unsigned int i; float f; } h; h.i = (unsigned)hi << 16;
  lo = f2bf(v - h.f);
}
__device__ __forceinline__ float f16u2f(unsigned int u){
  unsigned short s = (unsigned short)u; _Float16 h;
  __builtin_memcpy(&h, &s, 2); return (float)h;
}
__device__ __forceinline__ unsigned short f2f16u(float f){
  _Float16 h = (_Float16)f; unsigned short s;
  __builtin_memcpy(&s, &h, 2); return s;
}
__device__ __forceinline__ float fast_silu(float v){
  float e, r;
  asm("v_exp_f32 %0, %1" : "=v"(e) : "v"(v * -1.44269504088896f)); // exp(-v)
  asm("v_rcp_f32 %0, %1" : "=v"(r) : "v"(1.0f + e));
  return v * r;
}

// ---------------- merged: transpose (blk<800) + weight prep ----------------
__global__ __launch_bounds__(256) void k_pre(const float* __restrict__ x,
                                             const float* __restrict__ w_conv,
                                             const float* __restrict__ w_pconv,
                                             const float* __restrict__ gamma,
                                             const float* __restrict__ beta,
                                             const float* __restrict__ mean,
                                             const float* __restrict__ var,
                                             unsigned short* __restrict__ xt,
                                             unsigned short* __restrict__ xtl,
                                             uint4* __restrict__ wf,
                                             uint4* __restrict__ wpfH,
                                             uint4* __restrict__ wpfL,
                                             float* __restrict__ shift){
  __shared__ unsigned short tileH[64 * 132];
  __shared__ unsigned short tileL[64 * 132];
  int blk = blockIdx.x; int t = threadIdx.x;
  if (blk < 800){
    int b = blk / 100; int pixbase = (blk % 100) * 64;
    int lane = t & 63; int cg = t >> 6;
    for (int ci = 0; ci < 32; ++ci){
      int c = cg * 32 + ci;
      float v = x[(b * 128 + c) * NHW + pixbase + lane];
      unsigned short hi, lo; splitbf(v, hi, lo);
      tileH[lane * 132 + c] = hi;
      tileL[lane * 132 + c] = lo;
    }
    __syncthreads();
    for (int i = 0; i < 8; ++i){
      int slot = t + i * 256; int m = slot >> 5; int c = (slot & 31) * 4;
      uint2 vH = *reinterpret_cast<const uint2*>(&tileH[m * 132 + c]);
      uint2 vL = *reinterpret_cast<const uint2*>(&tileL[m * 132 + c]);
      *reinterpret_cast<uint2*>(xt  + (b * NHW + pixbase + m) * 128 + c) = vH;
      *reinterpret_cast<uint2*>(xtl + (b * NHW + pixbase + m) * 128 + c) = vL;
    }
    return;
  }
  int pblk = blk - 800;
  if (pblk < 144){
    int id = pblk * 256 + t;
    int lane = id & 63, ofrag = (id >> 6) & 15, kc = (id >> 10) & 3, n = id >> 12;
    int o = ofrag * 16 + (lane & 15), cb = kc * 32 + ((lane >> 4) & 3) * 8;
    float sc = gamma[o] * rsqrtf(var[o] + 1e-5f);       // BN scale folded in
    unsigned short h[8];
    for (int j = 0; j < 8; ++j) h[j] = f2bf(w_conv[(o * 128 + cb + j) * 9 + n] * sc);
    uint4 v;
    v.x = (unsigned)h[0] | ((unsigned)h[1] << 16);
    v.y = (unsigned)h[2] | ((unsigned)h[3] << 16);
    v.z = (unsigned)h[4] | ((unsigned)h[5] << 16);
    v.w = (unsigned)h[6] | ((unsigned)h[7] << 16);
    wf[id] = v;
  } else if (pblk < 180){
    int isLo = (pblk >= 162);
    int id = (pblk - (isLo ? 162 : 144)) * 256 + t;
    int lane = id & 63, ofrag = (id >> 6) & 1, kc = (id >> 7) & 3, tap = id >> 9;
    int o = ofrag * 16 + (lane & 15), cb = kc * 32 + ((lane >> 4) & 3) * 8;
    unsigned short h[8];
    for (int j = 0; j < 8; ++j){
      unsigned short hi = 0, lo = 0;
      if (o < 18) splitbf(w_pconv[(o * 128 + cb + j) * 9 + tap], hi, lo);
      h[j] = isLo ? lo : hi;
    }
    uint4 v;
    v.x = (unsigned)h[0] | ((unsigned)h[1] << 16);
    v.y = (unsigned)h[2] | ((unsigned)h[3] << 16);
    v.z = (unsigned)h[4] | ((unsigned)h[5] << 16);
    v.w = (unsigned)h[6] | ((unsigned)h[7] << 16);
    if (isLo) wpfL[id] = v; else wpfH[id] = v;
  } else {
    float sc = gamma[t] * rsqrtf(var[t] + 1e-5f);
    shift[t] = beta[t] - mean[t] * sc;
  }
}

// ---------------- fused: offset conv -> descL (LDS) -> barrier-free gather GEMM ----------------
// LDS map (22016 B): [0,17408) BtileH/L (phase 1 only; off_lds overlays
// [0,2560) after the tap loop's final barrier) | [17408,22016) descL
// (written end of phase 1, read-only broadcast in phase 2).
__global__ __launch_bounds__(256, 4) void k_fused(const unsigned short* __restrict__ xt,
                                                  const unsigned short* __restrict__ xtl,
                                                  const uint4* __restrict__ wpfH,
                                                  const uint4* __restrict__ wpfL,
                                                  const float* __restrict__ bpc,
                                                  const float* __restrict__ pn,
                                                  const uint4* __restrict__ wf,
                                                  const float* __restrict__ shift,
                                                  float* __restrict__ out){
  int bid = blockIdx.x;
  int blk = (bid & 7) * 200 + (bid >> 3);          // XCD swizzle (1600 % 8 == 0)
  int b = blk / 200; int pixbase = (blk % 200) * 32;
  int t = threadIdx.x; int lane = t & 63;

  __shared__ alignas(16) char smem[22016];
  short* BtileH  = (short*)(smem);                 // 32*136*2 = 8704 B
  short* BtileL  = (short*)(smem + 8704);          // 8704 B
  float* off_lds = (float*)(smem);                 // 2560 B overlay (Btile dead)
  uint4* descL   = (uint4*)(smem + 17408);         // 9*32*16 = 4608 B

  // ======================= phase 1: offset conv =======================
  {
    int wv = t >> 6; int og = wv & 1; int pf = wv >> 1;
    f32x4 acc = (f32x4){0.f, 0.f, 0.f, 0.f};
    const unsigned short* xbH = xt  + (size_t)b * NHW * 128;
    const unsigned short* xbL = xtl + (size_t)b * NHW * 128;

    int m_i[4], c_i[4], h_i[4], w_i[4];
#pragma unroll
    for (int i = 0; i < 4; ++i){
      int slot = t + i * 256;
      m_i[i] = slot >> 5; c_i[i] = (slot & 31) * 4;
      int p = pixbase + m_i[i];
      h_i[i] = p / NPIX; w_i[i] = p % NPIX;
    }

    uint2 rH[4], rL[4];

#define LOADTAP(DH, DW)                                                        \
  _Pragma("unroll")                                                            \
  for (int i = 0; i < 4; ++i){                                                 \
    int h2 = h_i[i] + (DH), w2 = w_i[i] + (DW);                                \
    uint2 vH; vH.x = 0u; vH.y = 0u;                                            \
    uint2 vL; vL.x = 0u; vL.y = 0u;                                            \
    if ((unsigned)h2 < NPIX && (unsigned)w2 < NPIX){                           \
      int off = (h2 * NPIX + w2) * 128 + c_i[i];                               \
      vH = *reinterpret_cast<const uint2*>(xbH + off);                         \
      vL = *reinterpret_cast<const uint2*>(xbL + off);                         \
    }                                                                          \
    rH[i] = vH; rL[i] = vL;                                                    \
  }

#define WRITETILE()                                                            \
  _Pragma("unroll")                                                            \
  for (int i = 0; i < 4; ++i){                                                 \
    *reinterpret_cast<uint2*>(&BtileH[m_i[i] * 136 + c_i[i]]) = rH[i];         \
    *reinterpret_cast<uint2*>(&BtileL[m_i[i] * 136 + c_i[i]]) = rL[i];         \
  }

    LOADTAP(-1, -1)
    WRITETILE()
    __syncthreads();

#pragma unroll 1
    for (int tap = 0; tap < 9; ++tap){
      if (tap < 8){
        int dh2 = (tap + 1) / 3 - 1, dw2 = (tap + 1) % 3 - 1;
        LOADTAP(dh2, dw2)
      }
#pragma unroll
      for (int kc = 0; kc < 4; ++kc){
        int boff = (pf * 16 + (lane & 15)) * 136 + kc * 32 + ((lane >> 4) & 3) * 8;
        bf16x8 bH = *reinterpret_cast<const bf16x8*>(&BtileH[boff]);
        bf16x8 bL = *reinterpret_cast<const bf16x8*>(&BtileL[boff]);
        int widx = ((tap * 4 + kc) * 2 + og) * 64 + lane;
        bf16x8 aH = *reinterpret_cast<const bf16x8*>(&wpfH[widx]);
        bf16x8 aL = *reinterpret_cast<const bf16x8*>(&wpfL[widx]);
        acc = __builtin_amdgcn_mfma_f32_16x16x32_bf16(aH, bH, acc, 0, 0, 0);
        acc = __builtin_amdgcn_mfma_f32_16x16x32_bf16(aH, bL, acc, 0, 0, 0);
        acc = __builtin_amdgcn_mfma_f32_16x16x32_bf16(aL, bH, acc, 0, 0, 0);
        acc = __builtin_amdgcn_mfma_f32_16x16x32_bf16(aL, bL, acc, 0, 0, 0);
      }
      __syncthreads();
      if (tap < 8){
        WRITETILE()
        __syncthreads();
      }
    }

    // off_lds overlays Btile[0,2560) — safe: the tap-8 __syncthreads above
    // guarantees every wave's last Btile read has completed.
    int pl = pf * 16 + (lane & 15);
#pragma unroll
    for (int r = 0; r < 4; ++r){
      int o = og * 16 + ((lane >> 4) & 3) * 4 + r;
      if (o < 18) off_lds[pl * 20 + o] = acc[r] + bpc[o];
    }
    __syncthreads();

    for (int item = t; item < 288; item += 256){
      int m = item / 9, n = item % 9;
      int p = pixbase + m; int h = p / NPIX, w = p % NPIX;
      float px = (float)h + pn[n]     + off_lds[m * 20 + n];
      float py = (float)w + pn[9 + n] + off_lds[m * 20 + 9 + n];
      float flx = floorf(px), fly = floorf(py);
      float qltx = fminf(fmaxf(flx, 0.f), 79.f);
      float qrbx = fminf(fmaxf(flx + 1.f, 0.f), 79.f);
      float qlty = fminf(fmaxf(fly, 0.f), 79.f);
      float qrby = fminf(fmaxf(fly + 1.f, 0.f), 79.f);
      float pcx = fminf(fmaxf(px, 0.f), 79.f);
      float pcy = fminf(fmaxf(py, 0.f), 79.f);
      float dxl = 1.f + (qltx - pcx), dxr = 1.f - (qrbx - pcx);
      float dyl = 1.f + (qlty - pcy), dyr = 1.f - (qrby - pcy);
      unsigned ix_l = (unsigned)(int)qltx, ix_r = (unsigned)(int)qrbx;
      unsigned iy_l = (unsigned)(int)qlty, iy_r = (unsigned)(int)qrby;
      uint4 d;
      d.x = (ix_l * NPIX + iy_l) | ((ix_r * NPIX + iy_r) << 16);
      d.y = (ix_l * NPIX + iy_r) | ((ix_r * NPIX + iy_l) << 16);
      d.z = (unsigned)f2f16u(dxl * dyl) | ((unsigned)f2f16u(dxr * dyr) << 16);
      d.w = (unsigned)f2f16u(dxl * dyr) | ((unsigned)f2f16u(dxr * dyl) << 16);
      descL[n * 32 + m] = d;
    }
#undef LOADTAP
#undef WRITETILE
  }
  __syncthreads();                 // descL visible — LAST barrier in kernel
  __builtin_amdgcn_sched_barrier(0);

  // ============ phase 2: barrier-free in-register gather GEMM ============
  // Wave wv owns px half pxh (16 px) x out-ch half oh (128 ch). Lane l:
  // px = pixbase + pxh*16 + (l&15); fragment bytes kc*64 + (l>>4)*16.
  // 36 kc-chunks; chunk i+1's 4 gathers issue before chunk i's MFMAs.
  {
    int wv = t >> 6;
    int pxh = wv & 1;
    int oh  = wv >> 1;
    int pxl = lane & 15;
    unsigned coff = (unsigned)((lane >> 4) * 16);
    int didx = pxh * 16 + pxl;
    const char* xb = (const char*)(xt + (size_t)b * NHW * 128);

    f32x4 acc[8];
#pragma unroll
    for (int of = 0; of < 8; ++of) acc[of] = (f32x4){0.f, 0.f, 0.f, 0.f};

    u32x4 Ga[4], Gb[4];          // depth-1 ping-pong (32 regs, proven budget)
    uint4 dcur, dnxt;
    float cw0, cw1, cw2, cw3, nw0, nw1, nw2, nw3;
    bf16x8 Bf;

#define GATHER(G, D, KC)                                                       \
  {                                                                            \
    G[0] = *reinterpret_cast<const u32x4*>(xb + (D.x & 0xffffu) * 256u + (KC) * 64u + coff); \
    G[1] = *reinterpret_cast<const u32x4*>(xb + (D.x >> 16)     * 256u + (KC) * 64u + coff); \
    G[2] = *reinterpret_cast<const u32x4*>(xb + (D.y & 0xffffu) * 256u + (KC) * 64u + coff); \
    G[3] = *reinterpret_cast<const u32x4*>(xb + (D.y >> 16)     * 256u + (KC) * 64u + coff); \
  }

#define COMBINE(G)                                                             \
  {                                                                            \
    u32x4 pk;                                                                  \
    _Pragma("unroll")                                                          \
    for (int j = 0; j < 4; ++j){                                               \
      f32x2 a = cw0 * bfp2f(G[0][j]) + cw1 * bfp2f(G[1][j])                    \
              + cw2 * bfp2f(G[2][j]) + cw3 * bfp2f(G[3][j]);                   \
      pk[j] = pk_bf16(a.x, a.y);                                               \
    }                                                                          \
    Bf = __builtin_bit_cast(bf16x8, pk);                                       \
  }

#define MFMA8(NN, KC)                                                          \
  {                                                                            \
    __builtin_amdgcn_s_setprio(1);                                             \
    _Pragma("unroll")                                                          \
    for (int of = 0; of < 8; ++of){                                            \
      bf16x8 afr = *reinterpret_cast<const bf16x8*>(                           \
          &wf[(((NN) * 4 + (KC)) * 16 + oh * 8 + of) * 64 + lane]);            \
      acc[of] = __builtin_amdgcn_mfma_f32_16x16x32_bf16(afr, Bf, acc[of], 0, 0, 0); \
    }                                                                          \
    __builtin_amdgcn_s_setprio(0);                                             \
  }

#define STEP(NN)                                                               \
  {                                                                            \
    GATHER(Gb, dcur, 1)                                                        \
    __builtin_amdgcn_sched_barrier(0);                                         \
    COMBINE(Ga) MFMA8(NN, 0)                                                   \
    GATHER(Ga, dcur, 2)                                                        \
    if ((NN) < 8){ dnxt = descL[((NN) + 1) * 32 + didx]; }                     \
    __builtin_amdgcn_sched_barrier(0);                                         \
    COMBINE(Gb) MFMA8(NN, 1)                                                   \
    GATHER(Gb, dcur, 3)                                                        \
    __builtin_amdgcn_sched_barrier(0);                                         \
    COMBINE(Ga) MFMA8(NN, 2)                                                   \
    if ((NN) < 8){                                                             \
      nw0 = f16u2f(dnxt.z & 0xffffu); nw1 = f16u2f(dnxt.z >> 16);              \
      nw2 = f16u2f(dnxt.w & 0xffffu); nw3 = f16u2f(dnxt.w >> 16);              \
      GATHER(Ga, dnxt, 0)                                                      \
    }                                                                          \
    __builtin_amdgcn_sched_barrier(0);                                         \
    COMBINE(Gb) MFMA8(NN, 3)                                                   \
    if ((NN) < 8){ dcur = dnxt; cw0 = nw0; cw1 = nw1; cw2 = nw2; cw3 = nw3; }  \
  }

    // prologue: step-0 desc + weights + first chunk's gathers
    dcur = descL[didx];
    cw0 = f16u2f(dcur.z & 0xffffu); cw1 = f16u2f(dcur.z >> 16);
    cw2 = f16u2f(dcur.w & 0xffffu); cw3 = f16u2f(dcur.w >> 16);
    GATHER(Ga, dcur, 0)

    STEP(0) STEP(1) STEP(2) STEP(3) STEP(4) STEP(5) STEP(6) STEP(7) STEP(8)

    // epilogue: +shift, fast SiLU, store
#pragma unroll
    for (int of = 0; of < 8; ++of){
      int o = oh * 128 + of * 16 + (lane >> 4) * 4;
      int pix = pixbase + pxh * 16 + pxl;
#pragma unroll
      for (int r = 0; r < 4; ++r){
        float v = acc[of][r] + shift[o + r];
        out[(size_t)(b * 256 + o + r) * NHW + pix] = fast_silu(v);
      }
    }
#undef GATHER
#undef COMBINE
#undef MFMA8
#undef STEP
  }
}

extern "C" void kernel_launch(void* const* d_in, const int* in_sizes, int n_in,
                              void* d_out, int out_size, void* d_ws, size_t ws_size,
                              hipStream_t stream){
  const float* x       = (const float*)d_in[0];
  const float* w_pconv = (const float*)d_in[1];
  const float* b_pconv = (const float*)d_in[2];
  const float* w_conv  = (const float*)d_in[3];
  const float* gamma   = (const float*)d_in[4];
  const float* beta    = (const float*)d_in[5];
  const float* mean    = (const float*)d_in[6];
  const float* var     = (const float*)d_in[7];
  const float* pn      = (const float*)d_in[8];

  char* ws = (char*)d_ws;
  unsigned short* xt  = (unsigned short*)(ws + 0);           // 13,107,200 B
  unsigned short* xtl = (unsigned short*)(ws + 13107200);    // 13,107,200 B
  // (desc region [26214400, 33587200) unused — kept for layout stability)
  uint4* wf           = (uint4*)(ws + 33587200);             //    589,824 B
  uint4* wpfH         = (uint4*)(ws + 34177024);             //     73,728 B
  uint4* wpfL         = (uint4*)(ws + 34250752);             //     73,728 B
  float* shift        = (float*)(ws + 34324480);             //      1,024 B
  float* out          = (float*)d_out;

  k_pre<<<981, 256, 0, stream>>>(x, w_conv, w_pconv, gamma, beta, mean, var,
                                 xt, xtl, wf, wpfH, wpfL, shift);
  k_fused<<<1600, 256, 0, stream>>>(xt, xtl, wpfH, wpfL, b_pconv, pn, wf, shift, out);
}

// Round 4
// 116.027 us; speedup vs baseline: 1.8242x; 1.8242x over previous
//
#include <hip/hip_runtime.h>
#include <hip/hip_bf16.h>

// LDConv (deformable sampling + (N,1) conv + BN + SiLU) for MI355X.
//
// Round-17 = R15 base (proven 114.6 us; R16's fragment-layout gather REVERTED
// — it amplified VMEM transactions 8x: 16x64B segments/instr vs 4x256B, plus
// 2x duplication -> 211 us) + queue-order-correct pipelining of phase 2:
//  - Mechanism being fixed: vmcnt retires IN ORDER. In R15 each MFMA_HALF's
//    streaming wf loads are YOUNGER than the step's gathers, so the first
//    MFMA's wf wait drains the gathers too -> per step ~2 full L2/HBM
//    latencies exposed (gathers issued only ~80cy before the drain).
//  - Fix: (1) W01 prefetch: wf frags for kc0-1 of step NN+1 loaded mid-step
//    NN *before* the data-NN+2 gathers are issued -> queue [W01|GX|GY];
//    MFMA01(NN+1) waits vmcnt(8): retires W01 only, gathers stay in flight.
//    W01's own latency hides under MFMA23(NN)'s wf drain.
//    (2) COMBs right after MFMA01; ISSUE_X/Y moved to step END -> gathers
//    get barrier + MFMA01 (~250-400cy) cover instead of ~80cy.
//    (3) desc loads one step earlier (DLD(NN+3) at step end).
//  - kc2-3 still streams wf (single-W-buffer constraint; its ~300cy drain
//    is accepted and doubles as W01 cover). Peak regs ~118 < 128 @ (256,4).
//    Spill tripwire: WRITE_SIZE must stay ~51 MB.
// Carried from R15: fused phase-1 offset conv -> descL in LDS, XCD swizzle,
// XOR-swizzled 16KB dbuf A_lds, BN scale folded into wf, fast SiLU, setprio.

typedef __attribute__((ext_vector_type(8))) short bf16x8;
typedef __attribute__((ext_vector_type(4))) float f32x4;
typedef __attribute__((ext_vector_type(2))) float f32x2;
typedef __attribute__((ext_vector_type(4))) unsigned int u32x4;

#define NHW 6400
#define NPIX 80

__device__ __forceinline__ unsigned short f2bf(float f){
  __hip_bfloat16 h = __float2bfloat16(f);
  unsigned short u; __builtin_memcpy(&u, &h, 2); return u;
}
__device__ __forceinline__ f32x2 bfp2f(unsigned int u){
  union { unsigned int i; float f; } a, b;
  a.i = u << 16; b.i = u & 0xffff0000u;
  f32x2 r; r.x = a.f; r.y = b.f; return r;
}
__device__ __forceinline__ unsigned pk_bf16(float a, float b){
  unsigned r;
  asm("v_cvt_pk_bf16_f32 %0, %1, %2" : "=v"(r) : "v"(a), "v"(b));
  return r;
}
__device__ __forceinline__ void splitbf(float v, unsigned short& hi, unsigned short& lo){
  hi = f2bf(v);
  union { unsigned int i; float f; } h; h.i = (unsigned)hi << 16;
  lo = f2bf(v - h.f);
}
__device__ __forceinline__ float f16u2f(unsigned int u){
  unsigned short s = (unsigned short)u; _Float16 h;
  __builtin_memcpy(&h, &s, 2); return (float)h;
}
__device__ __forceinline__ unsigned short f2f16u(float f){
  _Float16 h = (_Float16)f; unsigned short s;
  __builtin_memcpy(&s, &h, 2); return s;
}
__device__ __forceinline__ float fast_silu(float v){
  float e, r;
  asm("v_exp_f32 %0, %1" : "=v"(e) : "v"(v * -1.44269504088896f)); // exp(-v)
  asm("v_rcp_f32 %0, %1" : "=v"(r) : "v"(1.0f + e));
  return v * r;
}

// ---------------- merged: transpose (blk<800) + weight prep ----------------
__global__ __launch_bounds__(256) void k_pre(const float* __restrict__ x,
                                             const float* __restrict__ w_conv,
                                             const float* __restrict__ w_pconv,
                                             const float* __restrict__ gamma,
                                             const float* __restrict__ beta,
                                             const float* __restrict__ mean,
                                             const float* __restrict__ var,
                                             unsigned short* __restrict__ xt,
                                             unsigned short* __restrict__ xtl,
                                             uint4* __restrict__ wf,
                                             uint4* __restrict__ wpfH,
                                             uint4* __restrict__ wpfL,
                                             float* __restrict__ shift){
  __shared__ unsigned short tileH[64 * 132];
  __shared__ unsigned short tileL[64 * 132];
  int blk = blockIdx.x; int t = threadIdx.x;
  if (blk < 800){
    int b = blk / 100; int pixbase = (blk % 100) * 64;
    int lane = t & 63; int cg = t >> 6;
    for (int ci = 0; ci < 32; ++ci){
      int c = cg * 32 + ci;
      float v = x[(b * 128 + c) * NHW + pixbase + lane];
      unsigned short hi, lo; splitbf(v, hi, lo);
      tileH[lane * 132 + c] = hi;
      tileL[lane * 132 + c] = lo;
    }
    __syncthreads();
    for (int i = 0; i < 8; ++i){
      int slot = t + i * 256; int m = slot >> 5; int c = (slot & 31) * 4;
      uint2 vH = *reinterpret_cast<const uint2*>(&tileH[m * 132 + c]);
      uint2 vL = *reinterpret_cast<const uint2*>(&tileL[m * 132 + c]);
      *reinterpret_cast<uint2*>(xt  + (b * NHW + pixbase + m) * 128 + c) = vH;
      *reinterpret_cast<uint2*>(xtl + (b * NHW + pixbase + m) * 128 + c) = vL;
    }
    return;
  }
  int pblk = blk - 800;
  if (pblk < 144){
    int id = pblk * 256 + t;
    int lane = id & 63, ofrag = (id >> 6) & 15, kc = (id >> 10) & 3, n = id >> 12;
    int o = ofrag * 16 + (lane & 15), cb = kc * 32 + ((lane >> 4) & 3) * 8;
    float sc = gamma[o] * rsqrtf(var[o] + 1e-5f);       // BN scale folded in
    unsigned short h[8];
    for (int j = 0; j < 8; ++j) h[j] = f2bf(w_conv[(o * 128 + cb + j) * 9 + n] * sc);
    uint4 v;
    v.x = (unsigned)h[0] | ((unsigned)h[1] << 16);
    v.y = (unsigned)h[2] | ((unsigned)h[3] << 16);
    v.z = (unsigned)h[4] | ((unsigned)h[5] << 16);
    v.w = (unsigned)h[6] | ((unsigned)h[7] << 16);
    wf[id] = v;
  } else if (pblk < 180){
    int isLo = (pblk >= 162);
    int id = (pblk - (isLo ? 162 : 144)) * 256 + t;
    int lane = id & 63, ofrag = (id >> 6) & 1, kc = (id >> 7) & 3, tap = id >> 9;
    int o = ofrag * 16 + (lane & 15), cb = kc * 32 + ((lane >> 4) & 3) * 8;
    unsigned short h[8];
    for (int j = 0; j < 8; ++j){
      unsigned short hi = 0, lo = 0;
      if (o < 18) splitbf(w_pconv[(o * 128 + cb + j) * 9 + tap], hi, lo);
      h[j] = isLo ? lo : hi;
    }
    uint4 v;
    v.x = (unsigned)h[0] | ((unsigned)h[1] << 16);
    v.y = (unsigned)h[2] | ((unsigned)h[3] << 16);
    v.z = (unsigned)h[4] | ((unsigned)h[5] << 16);
    v.w = (unsigned)h[6] | ((unsigned)h[7] << 16);
    if (isLo) wpfL[id] = v; else wpfH[id] = v;
  } else {
    float sc = gamma[t] * rsqrtf(var[t] + 1e-5f);
    shift[t] = beta[t] - mean[t] * sc;
  }
}

// ---------------- fused: offset conv -> descL (LDS) -> pipelined gather GEMM ----------------
// LDS map (24576 B): [0,17408) BtileH/L  | [17408,19968) off_lds
//                    [0,16384)  A_lds[2] (phase 2, after barrier)
//                    [19968,24576) descL (persists across phases)
__global__ __launch_bounds__(256, 4) void k_fused(const unsigned short* __restrict__ xt,
                                                  const unsigned short* __restrict__ xtl,
                                                  const uint4* __restrict__ wpfH,
                                                  const uint4* __restrict__ wpfL,
                                                  const float* __restrict__ bpc,
                                                  const float* __restrict__ pn,
                                                  const uint4* __restrict__ wf,
                                                  const float* __restrict__ shift,
                                                  float* __restrict__ out){
  int bid = blockIdx.x;
  int blk = (bid & 7) * 200 + (bid >> 3);          // XCD swizzle (1600 % 8 == 0)
  int b = blk / 200; int pixbase = (blk % 200) * 32;
  int t = threadIdx.x; int lane = t & 63;

  __shared__ alignas(16) char smem[24576];
  short* BtileH  = (short*)(smem);                 // 32*136*2 = 8704 B
  short* BtileL  = (short*)(smem + 8704);          // 8704 B
  float* off_lds = (float*)(smem + 17408);         // 32*20*4 = 2560 B
  uint4* descL   = (uint4*)(smem + 19968);         // 9*32*16 = 4608 B

  // ======================= phase 1: offset conv =======================
  {
    int wv = t >> 6; int og = wv & 1; int pf = wv >> 1;
    f32x4 acc = (f32x4){0.f, 0.f, 0.f, 0.f};
    const unsigned short* xbH = xt  + (size_t)b * NHW * 128;
    const unsigned short* xbL = xtl + (size_t)b * NHW * 128;

    int m_i[4], c_i[4], h_i[4], w_i[4];
#pragma unroll
    for (int i = 0; i < 4; ++i){
      int slot = t + i * 256;
      m_i[i] = slot >> 5; c_i[i] = (slot & 31) * 4;
      int p = pixbase + m_i[i];
      h_i[i] = p / NPIX; w_i[i] = p % NPIX;
    }

    uint2 rH[4], rL[4];

#define LOADTAP(DH, DW)                                                        \
  _Pragma("unroll")                                                            \
  for (int i = 0; i < 4; ++i){                                                 \
    int h2 = h_i[i] + (DH), w2 = w_i[i] + (DW);                                \
    uint2 vH; vH.x = 0u; vH.y = 0u;                                            \
    uint2 vL; vL.x = 0u; vL.y = 0u;                                            \
    if ((unsigned)h2 < NPIX && (unsigned)w2 < NPIX){                           \
      int off = (h2 * NPIX + w2) * 128 + c_i[i];                               \
      vH = *reinterpret_cast<const uint2*>(xbH + off);                         \
      vL = *reinterpret_cast<const uint2*>(xbL + off);                         \
    }                                                                          \
    rH[i] = vH; rL[i] = vL;                                                    \
  }

#define WRITETILE()                                                            \
  _Pragma("unroll")                                                            \
  for (int i = 0; i < 4; ++i){                                                 \
    *reinterpret_cast<uint2*>(&BtileH[m_i[i] * 136 + c_i[i]]) = rH[i];         \
    *reinterpret_cast<uint2*>(&BtileL[m_i[i] * 136 + c_i[i]]) = rL[i];         \
  }

    LOADTAP(-1, -1)
    WRITETILE()
    __syncthreads();

#pragma unroll 1
    for (int tap = 0; tap < 9; ++tap){
      if (tap < 8){
        int dh2 = (tap + 1) / 3 - 1, dw2 = (tap + 1) % 3 - 1;
        LOADTAP(dh2, dw2)
      }
#pragma unroll
      for (int kc = 0; kc < 4; ++kc){
        int boff = (pf * 16 + (lane & 15)) * 136 + kc * 32 + ((lane >> 4) & 3) * 8;
        bf16x8 bH = *reinterpret_cast<const bf16x8*>(&BtileH[boff]);
        bf16x8 bL = *reinterpret_cast<const bf16x8*>(&BtileL[boff]);
        int widx = ((tap * 4 + kc) * 2 + og) * 64 + lane;
        bf16x8 aH = *reinterpret_cast<const bf16x8*>(&wpfH[widx]);
        bf16x8 aL = *reinterpret_cast<const bf16x8*>(&wpfL[widx]);
        acc = __builtin_amdgcn_mfma_f32_16x16x32_bf16(aH, bH, acc, 0, 0, 0);
        acc = __builtin_amdgcn_mfma_f32_16x16x32_bf16(aH, bL, acc, 0, 0, 0);
        acc = __builtin_amdgcn_mfma_f32_16x16x32_bf16(aL, bH, acc, 0, 0, 0);
        acc = __builtin_amdgcn_mfma_f32_16x16x32_bf16(aL, bL, acc, 0, 0, 0);
      }
      __syncthreads();
      if (tap < 8){
        WRITETILE()
        __syncthreads();
      }
    }

    int pl = pf * 16 + (lane & 15);
#pragma unroll
    for (int r = 0; r < 4; ++r){
      int o = og * 16 + ((lane >> 4) & 3) * 4 + r;
      if (o < 18) off_lds[pl * 20 + o] = acc[r] + bpc[o];
    }
    __syncthreads();

    for (int item = t; item < 288; item += 256){
      int m = item / 9, n = item % 9;
      int p = pixbase + m; int h = p / NPIX, w = p % NPIX;
      float px = (float)h + pn[n]     + off_lds[m * 20 + n];
      float py = (float)w + pn[9 + n] + off_lds[m * 20 + 9 + n];
      float flx = floorf(px), fly = floorf(py);
      float qltx = fminf(fmaxf(flx, 0.f), 79.f);
      float qrbx = fminf(fmaxf(flx + 1.f, 0.f), 79.f);
      float qlty = fminf(fmaxf(fly, 0.f), 79.f);
      float qrby = fminf(fmaxf(fly + 1.f, 0.f), 79.f);
      float pcx = fminf(fmaxf(px, 0.f), 79.f);
      float pcy = fminf(fmaxf(py, 0.f), 79.f);
      float dxl = 1.f + (qltx - pcx), dxr = 1.f - (qrbx - pcx);
      float dyl = 1.f + (qlty - pcy), dyr = 1.f - (qrby - pcy);
      unsigned ix_l = (unsigned)(int)qltx, ix_r = (unsigned)(int)qrbx;
      unsigned iy_l = (unsigned)(int)qlty, iy_r = (unsigned)(int)qrby;
      uint4 d;
      d.x = (ix_l * NPIX + iy_l) | ((ix_r * NPIX + iy_r) << 16);
      d.y = (ix_l * NPIX + iy_r) | ((ix_r * NPIX + iy_l) << 16);
      d.z = (unsigned)f2f16u(dxl * dyl) | ((unsigned)f2f16u(dxr * dyr) << 16);
      d.w = (unsigned)f2f16u(dxl * dyr) | ((unsigned)f2f16u(dxr * dyl) << 16);
      descL[n * 32 + m] = d;
    }
#undef LOADTAP
#undef WRITETILE
  }
  __syncthreads();                 // descL visible; Btile region dead
  __builtin_amdgcn_sched_barrier(0);

  // ======================= phase 2: pipelined gather GEMM =======================
  // Steady-state vmcnt queue at each point (oldest first):
  //   entering STEP(NN):            [W01(NN) x8 | GX(NN+1) x4 | GY(NN+1) x4]
  //   MFMA01 wait: vmcnt(8)  -> retires only W01; gathers keep flying.
  //   COMB_X: vmcnt(4); COMB_Y: vmcnt(0).
  //   then WLOAD01(NN+1) x8, MFMA23 streams wf23 x8 (drain covers W01),
  //   then ISSUE_X/Y(NN+2) x8 issued LAST -> youngest -> full-step cover.
  {
    int ow = t >> 6;
    char* A_lds0 = smem;                 // A_lds[buf] = smem + buf*8192
    const char* xb = (const char*)(xt + (size_t)b * NHW * 128);

    int m0 = t >> 4;            // row 0..15
    int m1 = m0 + 16;           // row 16..31
    int cb = (t & 15) * 16;     // byte col 0..240
    int ls0 = m0 * 256 + (cb ^ ((m0 & 7) << 4));
    int ls1 = m1 * 256 + (cb ^ ((m1 & 7) << 4));

    f32x4 acc[4][2];
#pragma unroll
    for (int of = 0; of < 4; ++of)
#pragma unroll
      for (int pf = 0; pf < 2; ++pf)
        acc[of][pf] = (f32x4){0.f, 0.f, 0.f, 0.f};

    u32x4 GX[4], GY[4];          // both live across the step boundary (32 regs)
    uint2 zwX, zwY;
    uint4 dB0, dB1;
    bf16x8 W01[8];               // kc0-1 weight prefetch (32 regs, single buffer)

#define DLD(N, M) descL[(N) * 32 + (M)]

#define ISSUE_X()                                                              \
  {                                                                            \
    zwX.x = dB0.z; zwX.y = dB0.w;                                              \
    GX[0] = *reinterpret_cast<const u32x4*>(xb + (dB0.x & 0xffffu) * 256u + (unsigned)cb); \
    GX[1] = *reinterpret_cast<const u32x4*>(xb + (dB0.x >> 16)     * 256u + (unsigned)cb); \
    GX[2] = *reinterpret_cast<const u32x4*>(xb + (dB0.y & 0xffffu) * 256u + (unsigned)cb); \
    GX[3] = *reinterpret_cast<const u32x4*>(xb + (dB0.y >> 16)     * 256u + (unsigned)cb); \
  }

#define ISSUE_Y()                                                              \
  {                                                                            \
    zwY.x = dB1.z; zwY.y = dB1.w;                                              \
    GY[0] = *reinterpret_cast<const u32x4*>(xb + (dB1.x & 0xffffu) * 256u + (unsigned)cb); \
    GY[1] = *reinterpret_cast<const u32x4*>(xb + (dB1.x >> 16)     * 256u + (unsigned)cb); \
    GY[2] = *reinterpret_cast<const u32x4*>(xb + (dB1.y & 0xffffu) * 256u + (unsigned)cb); \
    GY[3] = *reinterpret_cast<const u32x4*>(xb + (dB1.y >> 16)     * 256u + (unsigned)cb); \
  }

#define COMB(G, ZW, LSO, WB)                                                   \
  {                                                                            \
    float w0 = f16u2f(ZW.x & 0xffffu), w1 = f16u2f(ZW.x >> 16);                \
    float w2 = f16u2f(ZW.y & 0xffffu), w3 = f16u2f(ZW.y >> 16);                \
    u32x4 pk;                                                                  \
    _Pragma("unroll")                                                          \
    for (int j = 0; j < 4; ++j){                                               \
      f32x2 a = w0 * bfp2f(G[0][j]) + w1 * bfp2f(G[1][j])                      \
              + w2 * bfp2f(G[2][j]) + w3 * bfp2f(G[3][j]);                     \
      pk[j] = pk_bf16(a.x, a.y);                                               \
    }                                                                          \
    *reinterpret_cast<u32x4*>((WB) + (LSO)) = pk;                              \
  }

// prefetch wf fragments for kc0-1 of step NN (8 frags -> W01)
#define WLOAD01(NN)                                                            \
  {                                                                            \
    _Pragma("unroll")                                                          \
    for (int j = 0; j < 8; ++j){                                               \
      int kc = j >> 2; int of = j & 3;                                         \
      W01[j] = *reinterpret_cast<const bf16x8*>(                               \
          &wf[((((NN) * 4 + kc) * 16) + ow * 4 + of) * 64 + lane]);            \
    }                                                                          \
  }

// MFMA kc0-1 from prefetched W01 (no VMEM issued here)
#define MFMA_P01(NN)                                                           \
  {                                                                            \
    const char* ab = A_lds0 + ((NN) & 1) * 8192;                               \
    __builtin_amdgcn_s_setprio(1);                                             \
    _Pragma("unroll")                                                          \
    for (int kc = 0; kc <= 1; ++kc){                                           \
      bf16x8 bfrk[2];                                                          \
      _Pragma("unroll")                                                        \
      for (int pf = 0; pf < 2; ++pf){                                          \
        int row = pf * 16 + (lane & 15);                                       \
        bfrk[pf] = *reinterpret_cast<const bf16x8*>(                           \
            ab + row * 256 + ((kc * 64 + ((lane >> 4) & 3) * 16) ^ ((row & 7) << 4))); \
      }                                                                        \
      _Pragma("unroll")                                                        \
      for (int of = 0; of < 4; ++of){                                          \
        bf16x8 afr = W01[kc * 4 + of];                                         \
        _Pragma("unroll")                                                      \
        for (int pf = 0; pf < 2; ++pf)                                         \
          acc[of][pf] = __builtin_amdgcn_mfma_f32_16x16x32_bf16(afr, bfrk[pf], acc[of][pf], 0, 0, 0); \
      }                                                                        \
    }                                                                          \
    __builtin_amdgcn_s_setprio(0);                                             \
  }

// MFMA kc2-3 streaming wf (its drain also completes the fresh W01 prefetch)
#define MFMA_S23(NN)                                                           \
  {                                                                            \
    const char* ab = A_lds0 + ((NN) & 1) * 8192;                               \
    __builtin_amdgcn_s_setprio(1);                                             \
    _Pragma("unroll")                                                          \
    for (int kc = 2; kc <= 3; ++kc){                                           \
      bf16x8 bfrk[2];                                                          \
      _Pragma("unroll")                                                        \
      for (int pf = 0; pf < 2; ++pf){                                          \
        int row = pf * 16 + (lane & 15);                                       \
        bfrk[pf] = *reinterpret_cast<const bf16x8*>(                           \
            ab + row * 256 + ((kc * 64 + ((lane >> 4) & 3) * 16) ^ ((row & 7) << 4))); \
      }                                                                        \
      _Pragma("unroll")                                                        \
      for (int of = 0; of < 4; ++of){                                          \
        bf16x8 afr = *reinterpret_cast<const bf16x8*>(                         \
            &wf[((((NN) * 4 + kc) * 16) + ow * 4 + of) * 64 + lane]);          \
        _Pragma("unroll")                                                      \
        for (int pf = 0; pf < 2; ++pf)                                         \
          acc[of][pf] = __builtin_amdgcn_mfma_f32_16x16x32_bf16(afr, bfrk[pf], acc[of][pf], 0, 0, 0); \
      }                                                                        \
    }                                                                          \
    __builtin_amdgcn_s_setprio(0);                                             \
  }

// STEP(NN): MFMA01 (prefetched W01, vmcnt leaves gathers flying) | COMB_X+Y
//           (consume data NN+1 -> buf NN+1) | WLOAD01(NN+1) | MFMA23
//           (streaming wf23; drain covers W01) | ISSUE_X+Y (data NN+2,
//           youngest in queue -> full-step cover) | desc(NN+3) | barrier.
#define STEP(NN)                                                               \
  {                                                                            \
    MFMA_P01(NN)                                                               \
    if ((NN) < 8){                                                             \
      COMB(GX, zwX, ls0, A_lds0 + (((NN) + 1) & 1) * 8192)                     \
      COMB(GY, zwY, ls1, A_lds0 + (((NN) + 1) & 1) * 8192)                     \
    }                                                                          \
    __builtin_amdgcn_sched_barrier(0);                                         \
    if ((NN) < 8){ WLOAD01((NN) + 1) }                                         \
    __builtin_amdgcn_sched_barrier(0);                                         \
    MFMA_S23(NN)                                                               \
    __builtin_amdgcn_sched_barrier(0);                                         \
    if ((NN) < 7){ ISSUE_X() ISSUE_Y() }                                       \
    if ((NN) < 6){ dB0 = DLD((NN) + 3, m0); dB1 = DLD((NN) + 3, m1); }         \
    __syncthreads();                                                           \
  }

    // prologue: data0 gathered+combined into buf0; W01(0) prefetched BEFORE
    // data1 gathers so the steady-state queue order holds entering STEP(0).
    dB0 = DLD(0, m0); dB1 = DLD(0, m1);
    ISSUE_X() ISSUE_Y()                         // data 0
    COMB(GX, zwX, ls0, A_lds0)
    COMB(GY, zwY, ls1, A_lds0)
    dB0 = DLD(1, m0); dB1 = DLD(1, m1);
    __builtin_amdgcn_sched_barrier(0);
    WLOAD01(0)
    __builtin_amdgcn_sched_barrier(0);
    ISSUE_X() ISSUE_Y()                         // data 1
    dB0 = DLD(2, m0); dB1 = DLD(2, m1);
    __syncthreads();

    STEP(0) STEP(1) STEP(2) STEP(3) STEP(4) STEP(5) STEP(6) STEP(7) STEP(8)

    // epilogue: +shift, fast SiLU, store
#pragma unroll
    for (int of = 0; of < 4; ++of)
#pragma unroll
      for (int pf = 0; pf < 2; ++pf){
        int pix = pixbase + pf * 16 + (lane & 15);
#pragma unroll
        for (int r = 0; r < 4; ++r){
          int o = ow * 64 + of * 16 + ((lane >> 4) & 3) * 4 + r;
          float v = acc[of][pf][r] + shift[o];
          out[(size_t)(b * 256 + o) * NHW + pix] = fast_silu(v);
        }
      }
#undef DLD
#undef ISSUE_X
#undef ISSUE_Y
#undef COMB
#undef WLOAD01
#undef MFMA_P01
#undef MFMA_S23
#undef STEP
  }
}

extern "C" void kernel_launch(void* const* d_in, const int* in_sizes, int n_in,
                              void* d_out, int out_size, void* d_ws, size_t ws_size,
                              hipStream_t stream){
  const float* x       = (const float*)d_in[0];
  const float* w_pconv = (const float*)d_in[1];
  const float* b_pconv = (const float*)d_in[2];
  const float* w_conv  = (const float*)d_in[3];
  const float* gamma   = (const float*)d_in[4];
  const float* beta    = (const float*)d_in[5];
  const float* mean    = (const float*)d_in[6];
  const float* var     = (const float*)d_in[7];
  const float* pn      = (const float*)d_in[8];

  char* ws = (char*)d_ws;
  unsigned short* xt  = (unsigned short*)(ws + 0);           // 13,107,200 B
  unsigned short* xtl = (unsigned short*)(ws + 13107200);    // 13,107,200 B
  // (desc region [26214400, 33587200) unused — kept for layout stability)
  uint4* wf           = (uint4*)(ws + 33587200);             //    589,824 B
  uint4* wpfH         = (uint4*)(ws + 34177024);             //     73,728 B
  uint4* wpfL         = (uint4*)(ws + 34250752);             //     73,728 B
  float* shift        = (float*)(ws + 34324480);             //      1,024 B
  float* out          = (float*)d_out;

  k_pre<<<981, 256, 0, stream>>>(x, w_conv, w_pconv, gamma, beta, mean, var,
                                 xt, xtl, wf, wpfH, wpfL, shift);
  k_fused<<<1600, 256, 0, stream>>>(xt, xtl, wpfH, wpfL, b_pconv, pn, wf, shift, out);
}